// Round 9
// baseline (268.846 us; speedup 1.0000x reference)
//
#include <hip/hip_runtime.h>
#include <hip/hip_fp16.h>
#include <math.h>

#define DIM 128
#define NN 50000
#define NE 600000
#define EPS 1e-5f
#define CAP 64        // per-dst bucket capacity; P(Poisson(12) > 64) ~ 5e-26
#define NB_PREP 256   // prep role blocks
#define NB_EDGE 586   // 586*256*4 = 600064 >= NE

struct H8 { __half2 h[4]; };   // 16 B of fp16 channels
struct F8 { float4 a, b; };    // 32 B of fp32 channels

typedef _Float16 f16x8 __attribute__((ext_vector_type(8)));
typedef float    f32x4 __attribute__((ext_vector_type(4)));

// fast GELU (tanh form), |err| < ~7e-4 absolute
__device__ __forceinline__ float gelu_fast(float x) {
    const float c1 = 2.3022085f;   // 0.7978845608 * 2 * log2(e)
    const float c2 = 0.1029437f;   // c1 * 0.044715
    const float x2 = x * x;
    const float z  = x * __builtin_fmaf(c2, x2, c1);
    const float u  = __builtin_amdgcn_exp2f(z);
    const float r  = __builtin_amdgcn_rcpf(1.f + u);
    return __builtin_fmaf(-x, r, x);
}

__device__ __forceinline__ float sigmoid_fast(float y) {
    const float u = __builtin_amdgcn_exp2f(-1.4426950409f * y);
    return __builtin_amdgcn_rcpf(1.f + u);
}

// ---------------------------------------------------------------------------
// Merged prep + edge bucketing (0 LDS everywhere -> full occupancy; the
// bucket atomics get the TLP they need, unlike R6's LDS-capped role blocks):
//   blocks [0,128):        BN-folded gate weights -> WABth, bA, w0p, w1p
//   blocks [128,256):      update weights -> Wct, bpu
//   blocks [256,256+586):  rec[dst*CAP+pos] = (src | ew15<<17, ef0h|ef1h<<16)
// ---------------------------------------------------------------------------
__global__ __launch_bounds__(256) void k_prep_bucket(
    const float* __restrict__ Wg1, const float* __restrict__ bg1,
    const float* __restrict__ bng, const float* __restrict__ bnb,
    const float* __restrict__ bnm, const float* __restrict__ bnv,
    const float* __restrict__ Wphi, const float* __restrict__ bphi,
    const float* __restrict__ Wu,
    const int* __restrict__ ei, const float* __restrict__ ew,
    const float* __restrict__ ef,
    __half* __restrict__ WABth, float* __restrict__ bA,
    float* __restrict__ w0p, float* __restrict__ w1p,
    __half* __restrict__ Wct, float* __restrict__ bpu,
    int* __restrict__ deg, int2* __restrict__ rec)
{
    if (blockIdx.x < 128) {
        const int k = blockIdx.x;      // 0..127
        const int t = threadIdx.x;     // 0..255 (fused col)
        const int c = t & 127;
        const float s = bng[c] * rsqrtf(bnv[c] + EPS);
        const float w = (t < 128) ? Wg1[k * DIM + c] : Wg1[(DIM + k) * DIM + c];
        WABth[t * DIM + k] = __float2half(w * s);
        if (k == 0 && t < 128) {
            const float tt = bnb[c] - bnm[c] * s;
            bA[c]  = bg1[c] * s + tt;
            w0p[c] = Wg1[256 * DIM + c] * s;
            w1p[c] = Wg1[257 * DIM + c] * s;
        }
    } else if (blockIdx.x < NB_PREP) {
        const int a = blockIdx.x - 128;   // 0..127
        const int j = threadIdx.x;        // use 0..127
        if (j < 128) {
            float acc = 0.f;
            #pragma unroll 8
            for (int k = 0; k < DIM; ++k)
                acc += Wphi[a * DIM + k] * Wu[(DIM + k) * DIM + j];
            Wct[j * 256 + a]       = __float2half(Wu[a * DIM + j]);   // Wu_top^T
            Wct[j * 256 + 128 + a] = __float2half(acc);               // Wpu^T
            if (a == 0) {
                float b = 0.f;
                #pragma unroll 8
                for (int k = 0; k < DIM; ++k)
                    b += bphi[k] * Wu[(DIM + k) * DIM + j];
                bpu[j] = b;
            }
        }
    } else {
        // ---- edge-bucket role (R5-verified record format) ----
        const int tid = (blockIdx.x - NB_PREP) * 256 + threadIdx.x;
        #pragma unroll
        for (int k = 0; k < 4; ++k) {
            const int e = tid + k * (NB_EDGE * 256);
            if (e < NE) {
                const int s = ei[e];
                const int d = ei[NE + e];
                const float2 efv = *(const float2*)(ef + 2 * e);
                const int ewq = (int)fminf(ew[e] * 32768.f + 0.5f, 32767.f);
                int2 r;
                r.x = s | (ewq << 17);
                r.y = (int)__half_as_ushort(__float2half(efv.x)) |
                      ((int)__half_as_ushort(__float2half(efv.y)) << 16);
                const int pos = atomicAdd(&deg[d], 1);
                if (pos < CAP)
                    rec[(size_t)d * CAP + pos] = r;
            }
        }
    }
}

// ---------------------------------------------------------------------------
// Node GEMM via MFMA, LDS-staged x-tile (R7-verified, 256 thr / 4 waves):
//   stage: x tile -> fp16 -> xs LDS + coalesced xh write (converted once);
//   MFMA:  wave wv owns output cols [wv*64, wv*64+64);
//   epilogue: acc -> xs/ys reuse, coalesced A/Bv write-out.
// ---------------------------------------------------------------------------
__global__ __launch_bounds__(256) void k_node_mfma(
    const float* __restrict__ x, const __half* __restrict__ WABth,
    const float* __restrict__ bA,
    __half* __restrict__ A, __half* __restrict__ Bv, __half* __restrict__ xh)
{
    __shared__ __half xs[64][136];   // staging / out-tile cols 0-127 (17.4 KB)
    __shared__ __half ys[64][136];   // out-tile cols 128-255        (17.4 KB)

    const int t    = threadIdx.x;
    const int wv   = t >> 6;
    const int lane = t & 63;
    const int n16  = lane & 15;
    const int quad = lane >> 4;
    const int m0   = blockIdx.x * 64;

    // ---- stage: 4 passes x 256 thr x 8 floats (coalesced), convert once ----
    #pragma unroll
    for (int i = 0; i < 4; ++i) {
        const int idx = i * 256 + t;          // 0..1023, 16 chunks per row
        const int row = idx >> 4;
        const int col = (idx & 15) * 8;
        const int grow = min(m0 + row, NN - 1);
        const float4 xa = *(const float4*)(x + (size_t)grow * DIM + col);
        const float4 xb = *(const float4*)(x + (size_t)grow * DIM + col + 4);
        f16x8 af;
        af[0] = (_Float16)xa.x; af[1] = (_Float16)xa.y;
        af[2] = (_Float16)xa.z; af[3] = (_Float16)xa.w;
        af[4] = (_Float16)xb.x; af[5] = (_Float16)xb.y;
        af[6] = (_Float16)xb.z; af[7] = (_Float16)xb.w;
        *(f16x8*)&xs[row][col] = af;
        *(f16x8*)(xh + (size_t)grow * DIM + col) = af;
    }
    __syncthreads();

    // ---- MFMA: wave wv owns output cols [wv*64, wv*64+64) ----
    f32x4 acc[4][4];
    #pragma unroll
    for (int mt = 0; mt < 4; ++mt)
        #pragma unroll
        for (int nt = 0; nt < 4; ++nt)
            acc[mt][nt] = (f32x4){0.f, 0.f, 0.f, 0.f};

    #pragma unroll
    for (int ks = 0; ks < 4; ++ks) {
        const int ko = ks * 32 + quad * 8;
        f16x8 bf[4];
        #pragma unroll
        for (int nt = 0; nt < 4; ++nt) {
            const int c = wv * 64 + nt * 16 + n16;
            bf[nt] = *(const f16x8*)(WABth + c * DIM + ko);
        }
        #pragma unroll
        for (int mt = 0; mt < 4; ++mt) {
            const f16x8 af = *(const f16x8*)&xs[mt * 16 + n16][ko];
            #pragma unroll
            for (int nt = 0; nt < 4; ++nt)
                acc[mt][nt] = __builtin_amdgcn_mfma_f32_16x16x32_f16(
                    af, bf[nt], acc[mt][nt], 0, 0, 0);
        }
    }
    __syncthreads();   // xs reuse hazard: all ds_reads done before overwrite

    // ---- epilogue: +bias, fp16, write into xs/ys out-tiles ----
    #pragma unroll
    for (int nt = 0; nt < 4; ++nt) {
        const int c = wv * 64 + nt * 16 + n16;
        const float bias = (c < 128) ? bA[c] : 0.f;
        #pragma unroll
        for (int mt = 0; mt < 4; ++mt)
            #pragma unroll
            for (int reg = 0; reg < 4; ++reg) {
                const int row = mt * 16 + quad * 4 + reg;
                const __half hv = __float2half(acc[mt][nt][reg] + bias);
                if (c < 128) xs[row][c]       = hv;
                else         ys[row][c - 128] = hv;
            }
    }
    __syncthreads();

    // ---- coalesced read-out: 2048 chunks of 16 B ----
    #pragma unroll
    for (int i = 0; i < 8; ++i) {
        const int chunk = t + i * 256;
        const int row = chunk >> 5;
        const int o   = (chunk & 31) * 8;   // half index 0..255
        if (m0 + row < NN) {
            if (o < 128) {
                const uint4 v = *(const uint4*)&xs[row][o];
                *(uint4*)(A + (size_t)(m0 + row) * DIM + o) = v;
            } else {
                const uint4 v = *(const uint4*)&ys[row][o - 128];
                *(uint4*)(Bv + (size_t)(m0 + row) * DIM + o - 128) = v;
            }
        }
    }
}

// ---------------------------------------------------------------------------
// Gate kernel, BUCKET-ORDERED, one WAVE per node (block = 4 waves = 4 nodes).
//   A[node] loaded ONCE per wave (vs ~12 random re-fetches in edge order);
//   records stream contiguously; Bv[src] is the only random gather.
//   Slot sub handles entries {j0, j0+1}, j0 = sub*2 + 8*iter (j0 even ->
//   16-B aligned int4; j0+1 <= 63 always in-bounds).
//   coef = ew * sigmoid(MLP) overwrites rec[].y in place (line L2-hot).
// ---------------------------------------------------------------------------
__global__ __launch_bounds__(256) void k_gate2(
    const int* __restrict__ deg, int2* __restrict__ rec,
    const __half* __restrict__ A, const __half* __restrict__ Bv,
    const float* __restrict__ w0p, const float* __restrict__ w1p,
    const float* __restrict__ Wg2, const float* __restrict__ bg2)
{
    const int t  = threadIdx.x;
    const int wv = t >> 6;
    const int n  = blockIdx.x * 4 + wv;      // one node per wave (grid exact)
    const int d  = min(deg[n], CAP);
    if (d == 0) return;

    const int lane = t & 63;
    const int sub  = lane >> 4;              // slot 0..3
    const int sl   = lane & 15;
    const int c8   = sl * 8;

    const H8 ar = *(const H8*)(A + (size_t)n * DIM + c8);

    const F8 W0 = *(const F8*)(w0p + c8);
    const F8 W1 = *(const F8*)(w1p + c8);
    const F8 WG = *(const F8*)(Wg2 + c8);
    const float bg2v = bg2[0];
    const float* w0 = (const float*)&W0;
    const float* w1 = (const float*)&W1;
    const float* wg = (const float*)&WG;

    const size_t base = (size_t)n * CAP;

    for (int j0 = sub * 2; j0 < d; j0 += 8) {
        const bool v1 = (j0 + 1 < d);

        const int4 pq = *(const int4*)(&rec[base + j0]);
        const int sx0 = pq.x & 0x1FFFF;
        const int sx1 = v1 ? (pq.z & 0x1FFFF) : 0;
        const float ew0 = (float)((unsigned)pq.x >> 17) * (1.f / 32768.f);
        const float ew1 = v1 ? (float)((unsigned)pq.z >> 17) * (1.f / 32768.f) : 0.f;
        const float2 ef0 = __half22float2(*(const __half2*)&pq.y);
        const float2 ef1 = __half22float2(*(const __half2*)&pq.w);

        const H8 b0 = *(const H8*)(Bv + (size_t)sx0 * DIM + c8);
        const H8 b1 = *(const H8*)(Bv + (size_t)sx1 * DIM + c8);

        float p0 = 0.f, p1 = 0.f;
        #pragma unroll
        for (int i = 0; i < 4; ++i) {
            const float2 s0 = __half22float2(__hadd2(ar.h[i], b0.h[i]));
            const float2 s1 = __half22float2(__hadd2(ar.h[i], b1.h[i]));
            const int c0 = 2 * i, c1 = 2 * i + 1;
            float h;
            h = s0.x + ef0.x * w0[c0] + ef0.y * w1[c0];
            p0 = __builtin_fmaf(gelu_fast(h), wg[c0], p0);
            h = s0.y + ef0.x * w0[c1] + ef0.y * w1[c1];
            p0 = __builtin_fmaf(gelu_fast(h), wg[c1], p0);
            h = s1.x + ef1.x * w0[c0] + ef1.y * w1[c0];
            p1 = __builtin_fmaf(gelu_fast(h), wg[c0], p1);
            h = s1.y + ef1.x * w0[c1] + ef1.y * w1[c1];
            p1 = __builtin_fmaf(gelu_fast(h), wg[c1], p1);
        }
        #pragma unroll
        for (int off = 1; off < 16; off <<= 1) {
            p0 += __shfl_xor(p0, off, 64);
            p1 += __shfl_xor(p1, off, 64);
        }

        if (sl == 0) {
            rec[base + j0].y = __float_as_int(ew0 * sigmoid_fast(p0 + bg2v));
            if (v1)
                rec[base + j0 + 1].y = __float_as_int(ew1 * sigmoid_fast(p1 + bg2v));
        }
    }
}

// ---------------------------------------------------------------------------
// Fused aggregation + update (R7-verified 2-wave version; only change:
// src index masked from the record's low 17 bits).
// ---------------------------------------------------------------------------
__global__ __launch_bounds__(128, 3) void k_agg_update(
    const int* __restrict__ deg, const int2* __restrict__ rec,
    const __half* __restrict__ xh, const __half* __restrict__ Wct,
    const float* __restrict__ bu, const float* __restrict__ bpu,
    const float* __restrict__ lng, const float* __restrict__ lnb,
    float* __restrict__ out)
{
    __shared__ __half xt[16][136];       // x tile fp16, +8 pad
    __shared__ __half at[2][16][136];    // per-wave agg tiles fp16
    __shared__ float  sct[2][16];
    __shared__ float  sred_s[2][16];     // per-wave LN partial sums
    __shared__ float  sred_ss[2][16];

    const int t    = threadIdx.x;        // 0..127
    const int w    = t >> 6;             // wave id 0/1
    const int lane = t & 63;
    const int n16  = lane & 15;
    const int quad = lane >> 4;          // 0..3
    const int m0   = blockIdx.x * 16;

    const int slot = quad;               // 4 slots of 16 lanes per wave
    const int sl   = n16;
    const int c8   = sl * 8;

    // ---- per-slot node state: this wave's half of each bucket ----
    int    cnt[4];
    size_t pb[4];
    #pragma unroll
    for (int r = 0; r < 4; ++r) {
        const int lr = r * 4 + slot;
        const int nc = min(m0 + lr, NN - 1);
        const int d  = min(deg[nc], CAP);
        const int h  = ((d + 2) >> 2) << 1;   // ~d/2 rounded to even, <= d
        const int lo = w ? h : 0;
        const int hi = w ? d : h;
        cnt[r] = hi - lo;
        pb[r]  = (size_t)nc * CAP + lo;
    }

    // ---- Phase 0: cooperative xh tile load (256 chunks / 128 thr) ----
    #pragma unroll
    for (int i = 0; i < 2; ++i) {
        const int idx = i * 128 + t;          // 8-half chunk id
        const int row = idx >> 4;             // 16 chunks per row
        const int col = (idx & 15) * 8;
        const int grow = min(m0 + row, NN - 1);
        *(f16x8*)&xt[row][col] = *(const f16x8*)(xh + (size_t)grow * DIM + col);
    }

    // ---- Phase 1: interleaved aggregation, 4 nodes x 4 edges per step ----
    float acc[4][8];
    float scn[4] = {0.f, 0.f, 0.f, 0.f};
    #pragma unroll
    for (int r = 0; r < 4; ++r)
        #pragma unroll
        for (int i = 0; i < 8; ++i) acc[r][i] = 0.f;

    const int cmax = max(max(cnt[0], cnt[1]), max(cnt[2], cnt[3]));

    for (int jj = 0; jj < cmax; jj += 4) {
        int4 pq0[4], pq1[4];
        #pragma unroll
        for (int r = 0; r < 4; ++r) {
            pq0[r] = *(const int4*)(&rec[pb[r] + jj]);
            pq1[r] = *(const int4*)(&rec[pb[r] + jj + 2]);
        }

        // branchless validity: invalid -> gather row 0 (L1-hot) with coef 0
        int   ix[16];
        float cf[16];
        #pragma unroll
        for (int r = 0; r < 4; ++r) {
            const int q = 4 * r;
            const bool v0 = (jj     < cnt[r]);
            const bool v1 = (jj + 1 < cnt[r]);
            const bool v2 = (jj + 2 < cnt[r]);
            const bool v3 = (jj + 3 < cnt[r]);
            ix[q]     = v0 ? (pq0[r].x & 0x1FFFF) : 0;
            cf[q]     = v0 ? __int_as_float(pq0[r].y) : 0.f;
            ix[q + 1] = v1 ? (pq0[r].z & 0x1FFFF) : 0;
            cf[q + 1] = v1 ? __int_as_float(pq0[r].w) : 0.f;
            ix[q + 2] = v2 ? (pq1[r].x & 0x1FFFF) : 0;
            cf[q + 2] = v2 ? __int_as_float(pq1[r].y) : 0.f;
            ix[q + 3] = v3 ? (pq1[r].z & 0x1FFFF) : 0;
            cf[q + 3] = v3 ? __int_as_float(pq1[r].w) : 0.f;
        }

        // 16 independent row gathers in flight
        H8 xv[16];
        #pragma unroll
        for (int q = 0; q < 16; ++q)
            xv[q] = *(const H8*)(xh + (size_t)ix[q] * DIM + c8);

        #pragma unroll
        for (int r = 0; r < 4; ++r) {
            #pragma unroll
            for (int k = 0; k < 4; ++k) {
                const int   q = 4 * r + k;
                const float c = cf[q];
                #pragma unroll
                for (int i = 0; i < 4; ++i) {
                    const float2 f = __half22float2(xv[q].h[i]);
                    acc[r][2 * i]     = __builtin_fmaf(c, f.x, acc[r][2 * i]);
                    acc[r][2 * i + 1] = __builtin_fmaf(c, f.y, acc[r][2 * i + 1]);
                }
                scn[r] += c;
            }
        }
    }

    #pragma unroll
    for (int r = 0; r < 4; ++r) {
        const int lr = r * 4 + slot;
        f16x8 hv;
        #pragma unroll
        for (int i = 0; i < 8; ++i) hv[i] = (_Float16)acc[r][i];
        *(f16x8*)&at[w][lr][c8] = hv;
        if (sl == 0) sct[w][lr] = scn[r];
    }
    __syncthreads();

    // ---- Phase 2: MFMA, wave w owns output channels [w*64, w*64+64) ----
    f32x4 acc2[4];
    #pragma unroll
    for (int nt = 0; nt < 4; ++nt) acc2[nt] = (f32x4){0.f, 0.f, 0.f, 0.f};

    const int rloc = n16;                     // A-fragment local row
    #pragma unroll
    for (int ks = 0; ks < 4; ++ks) {
        const int ko = ks * 32 + quad * 8;
        const f16x8 af = *(const f16x8*)&xt[rloc][ko];
        #pragma unroll
        for (int nt = 0; nt < 4; ++nt) {
            const int c = w * 64 + nt * 16 + n16;
            const f16x8 bf = *(const f16x8*)(Wct + c * 256 + ko);
            acc2[nt] = __builtin_amdgcn_mfma_f32_16x16x32_f16(af, bf, acc2[nt], 0, 0, 0);
        }
    }
    #pragma unroll
    for (int half = 0; half < 2; ++half) {
        #pragma unroll
        for (int ks = 0; ks < 4; ++ks) {
            const int ko = ks * 32 + quad * 8;
            const f16x8 af = *(const f16x8*)&at[half][rloc][ko];
            #pragma unroll
            for (int nt = 0; nt < 4; ++nt) {
                const int c = w * 64 + nt * 16 + n16;
                const f16x8 bf = *(const f16x8*)(Wct + c * 256 + 128 + ko);
                acc2[nt] = __builtin_amdgcn_mfma_f32_16x16x32_f16(af, bf, acc2[nt], 0, 0, 0);
            }
        }
    }

    // ---- epilogue ----
    int   rl[4];
    float scv[4];
    #pragma unroll
    for (int reg = 0; reg < 4; ++reg) {
        rl[reg]  = quad * 4 + reg;            // local row
        scv[reg] = sct[0][rl[reg]] + sct[1][rl[reg]];
    }

    float yv[4][4];
    float s[4]  = {0.f, 0.f, 0.f, 0.f};
    float ss[4] = {0.f, 0.f, 0.f, 0.f};

    #pragma unroll
    for (int nt = 0; nt < 4; ++nt) {
        const int c = w * 64 + nt * 16 + n16;
        const float buv = bu[c], bpv = bpu[c];
        #pragma unroll
        for (int reg = 0; reg < 4; ++reg) {
            float h = acc2[nt][reg] + buv + scv[reg] * bpv;
            h = gelu_fast(h);
            const float xv = __half2float(xt[rl[reg]][c]);   // residual from LDS
            const float y = xv + h;
            yv[nt][reg] = y;
            s[reg]  += y;
            ss[reg] += y * y;
        }
    }

    #pragma unroll
    for (int reg = 0; reg < 4; ++reg) {
        #pragma unroll
        for (int off = 1; off < 16; off <<= 1) {
            s[reg]  += __shfl_xor(s[reg],  off, 64);
            ss[reg] += __shfl_xor(ss[reg], off, 64);
        }
    }
    if (n16 == 0) {
        #pragma unroll
        for (int reg = 0; reg < 4; ++reg) {
            sred_s[w][rl[reg]]  = s[reg];
            sred_ss[w][rl[reg]] = ss[reg];
        }
    }
    __syncthreads();

    float mu[4], rs[4];
    #pragma unroll
    for (int reg = 0; reg < 4; ++reg) {
        const float stot  = sred_s[0][rl[reg]]  + sred_s[1][rl[reg]];
        const float sstot = sred_ss[0][rl[reg]] + sred_ss[1][rl[reg]];
        mu[reg] = stot * (1.f / DIM);
        const float var = sstot * (1.f / DIM) - mu[reg] * mu[reg];
        rs[reg] = rsqrtf(var + EPS);
    }

    #pragma unroll
    for (int nt = 0; nt < 4; ++nt) {
        const int c = w * 64 + nt * 16 + n16;
        const float gg = lng[c], bb2 = lnb[c];
        #pragma unroll
        for (int reg = 0; reg < 4; ++reg) {
            const int grow = m0 + rl[reg];
            if (grow < NN)
                __builtin_nontemporal_store(
                    (yv[nt][reg] - mu[reg]) * rs[reg] * gg + bb2,
                    &out[(size_t)grow * DIM + c]);
        }
    }
}

// ---------------------------------------------------------------------------
extern "C" void kernel_launch(void* const* d_in, const int* in_sizes, int n_in,
                              void* d_out, int out_size, void* d_ws, size_t ws_size,
                              hipStream_t stream)
{
    const float* x    = (const float*)d_in[0];
    const int*   ei   = (const int*)  d_in[1];
    const float* ew   = (const float*)d_in[2];
    const float* ef   = (const float*)d_in[3];
    const float* Wphi = (const float*)d_in[5];
    const float* bphi = (const float*)d_in[6];
    const float* Wg1  = (const float*)d_in[7];
    const float* bg1  = (const float*)d_in[8];
    const float* bng  = (const float*)d_in[9];
    const float* bnb  = (const float*)d_in[10];
    const float* bnm  = (const float*)d_in[11];
    const float* bnv  = (const float*)d_in[12];
    const float* Wg2  = (const float*)d_in[13];
    const float* bg2  = (const float*)d_in[14];
    const float* Wu   = (const float*)d_in[15];
    const float* bu   = (const float*)d_in[16];
    const float* lng  = (const float*)d_in[17];
    const float* lnb  = (const float*)d_in[18];

    float* out = (float*)d_out;

    char* wsb = (char*)d_ws;
    size_t off = 0;
    auto carve = [&](size_t bytes) -> void* {
        void* p = wsb + off;
        off += (bytes + 255) & ~(size_t)255;
        return p;
    };
    __half* xh    = (__half*)carve((size_t)NN * DIM * 2);
    __half* A     = (__half*)carve((size_t)NN * DIM * 2);
    __half* Bv    = (__half*)carve((size_t)NN * DIM * 2);
    __half* WABth = (__half*)carve(256 * DIM * 2);
    __half* Wct   = (__half*)carve(DIM * 256 * 2);
    float*  bA    = (float*) carve(DIM * 4);
    float*  w0p   = (float*) carve(DIM * 4);
    float*  w1p   = (float*) carve(DIM * 4);
    float*  bpu   = (float*) carve(DIM * 4);
    int*    deg   = (int*)   carve((size_t)NN * 4);
    int2*   rec   = (int2*)  carve((size_t)NN * CAP * 8 + 256);  // +tail slack

    hipMemsetAsync(deg, 0, (size_t)NN * 4, stream);

    k_prep_bucket<<<NB_PREP + NB_EDGE, 256, 0, stream>>>(
        Wg1, bg1, bng, bnb, bnm, bnv, Wphi, bphi, Wu, ei, ew, ef,
        WABth, bA, w0p, w1p, Wct, bpu, deg, rec);
    k_node_mfma<<<(NN + 63) / 64, 256, 0, stream>>>(x, WABth, bA, A, Bv, xh);
    k_gate2<<<NN / 4, 256, 0, stream>>>(deg, rec, A, Bv, w0p, w1p, Wg2, bg2);
    k_agg_update<<<(NN + 15) / 16, 128, 0, stream>>>(deg, rec, xh, Wct,
                                                     bu, bpu, lng, lnb, out);
}

// Round 10
// 249.252 us; speedup vs baseline: 1.0786x; 1.0786x over previous
//
#include <hip/hip_runtime.h>
#include <hip/hip_fp16.h>
#include <math.h>

#define DIM 128
#define NN 50000
#define NE 600000
#define EPS 1e-5f
#define CAP 64   // per-dst bucket capacity; P(Poisson(12) > 64) ~ 5e-26

struct H8 { __half2 h[4]; };   // 16 B of fp16 channels
struct F8 { float4 a, b; };    // 32 B of fp32 channels

typedef _Float16 f16x8 __attribute__((ext_vector_type(8)));
typedef float    f32x4 __attribute__((ext_vector_type(4)));

// fast GELU (tanh form), |err| < ~7e-4 absolute
__device__ __forceinline__ float gelu_fast(float x) {
    const float c1 = 2.3022085f;   // 0.7978845608 * 2 * log2(e)
    const float c2 = 0.1029437f;   // c1 * 0.044715
    const float x2 = x * x;
    const float z  = x * __builtin_fmaf(c2, x2, c1);
    const float u  = __builtin_amdgcn_exp2f(z);
    const float r  = __builtin_amdgcn_rcpf(1.f + u);
    return __builtin_fmaf(-x, r, x);
}

__device__ __forceinline__ float sigmoid_fast(float y) {
    const float u = __builtin_amdgcn_exp2f(-1.4426950409f * y);
    return __builtin_amdgcn_rcpf(1.f + u);
}

// ---------------------------------------------------------------------------
// Merged prep (role-split by blockIdx; R8-verified):
//   blocks [0,128):   fold BN scale into gate layer-1 -> WABth, bA, w0p, w1p
//   blocks [128,256): update weights -> Wct (Wu_top^T | (Wphi@Wu_bot)^T), bpu
// ---------------------------------------------------------------------------
__global__ __launch_bounds__(256) void k_prep(
    const float* __restrict__ Wg1, const float* __restrict__ bg1,
    const float* __restrict__ bng, const float* __restrict__ bnb,
    const float* __restrict__ bnm, const float* __restrict__ bnv,
    const float* __restrict__ Wphi, const float* __restrict__ bphi,
    const float* __restrict__ Wu,
    __half* __restrict__ WABth, float* __restrict__ bA,
    float* __restrict__ w0p, float* __restrict__ w1p,
    __half* __restrict__ Wct, float* __restrict__ bpu)
{
    if (blockIdx.x < 128) {
        const int k = blockIdx.x;      // 0..127
        const int t = threadIdx.x;     // 0..255 (fused col)
        const int c = t & 127;
        const float s = bng[c] * rsqrtf(bnv[c] + EPS);
        const float w = (t < 128) ? Wg1[k * DIM + c] : Wg1[(DIM + k) * DIM + c];
        WABth[t * DIM + k] = __float2half(w * s);
        if (k == 0 && t < 128) {
            const float tt = bnb[c] - bnm[c] * s;
            bA[c]  = bg1[c] * s + tt;
            w0p[c] = Wg1[256 * DIM + c] * s;
            w1p[c] = Wg1[257 * DIM + c] * s;
        }
    } else {
        const int a = blockIdx.x - 128;   // 0..127
        const int j = threadIdx.x;        // use 0..127
        if (j < 128) {
            float acc = 0.f;
            #pragma unroll 8
            for (int k = 0; k < DIM; ++k)
                acc += Wphi[a * DIM + k] * Wu[(DIM + k) * DIM + j];
            Wct[j * 256 + a]       = __float2half(Wu[a * DIM + j]);   // Wu_top^T
            Wct[j * 256 + 128 + a] = __float2half(acc);               // Wpu^T
            if (a == 0) {
                float b = 0.f;
                #pragma unroll 8
                for (int k = 0; k < DIM; ++k)
                    b += bphi[k] * Wu[(DIM + k) * DIM + j];
                bpu[j] = b;
            }
        }
    }
}

// ---------------------------------------------------------------------------
// Node GEMM via MFMA, LDS-staged x-tile (R7-verified, 256 thr / 4 waves).
// Also zeroes deg[] (782 blocks x 256 thr cover 50k ints) -> the standalone
// hipMemsetAsync dispatch is dropped (runs strictly before k_gate).
// ---------------------------------------------------------------------------
__global__ __launch_bounds__(256) void k_node_mfma(
    const float* __restrict__ x, const __half* __restrict__ WABth,
    const float* __restrict__ bA,
    __half* __restrict__ A, __half* __restrict__ Bv, __half* __restrict__ xh,
    int* __restrict__ deg)
{
    __shared__ __half xs[64][136];   // staging / out-tile cols 0-127 (17.4 KB)
    __shared__ __half ys[64][136];   // out-tile cols 128-255        (17.4 KB)

    const int t    = threadIdx.x;
    const int wv   = t >> 6;
    const int lane = t & 63;
    const int n16  = lane & 15;
    const int quad = lane >> 4;
    const int m0   = blockIdx.x * 64;

    // ---- deg zeroing (replaces hipMemsetAsync; deg unused in this kernel) --
    {
        const int z = blockIdx.x * 256 + t;
        if (z < NN) deg[z] = 0;
    }

    // ---- stage: 4 passes x 256 thr x 8 floats (coalesced), convert once ----
    #pragma unroll
    for (int i = 0; i < 4; ++i) {
        const int idx = i * 256 + t;          // 0..1023, 16 chunks per row
        const int row = idx >> 4;
        const int col = (idx & 15) * 8;
        const int grow = min(m0 + row, NN - 1);
        const float4 xa = *(const float4*)(x + (size_t)grow * DIM + col);
        const float4 xb = *(const float4*)(x + (size_t)grow * DIM + col + 4);
        f16x8 af;
        af[0] = (_Float16)xa.x; af[1] = (_Float16)xa.y;
        af[2] = (_Float16)xa.z; af[3] = (_Float16)xa.w;
        af[4] = (_Float16)xb.x; af[5] = (_Float16)xb.y;
        af[6] = (_Float16)xb.z; af[7] = (_Float16)xb.w;
        *(f16x8*)&xs[row][col] = af;
        *(f16x8*)(xh + (size_t)grow * DIM + col) = af;
    }
    __syncthreads();

    // ---- MFMA: wave wv owns output cols [wv*64, wv*64+64) ----
    f32x4 acc[4][4];
    #pragma unroll
    for (int mt = 0; mt < 4; ++mt)
        #pragma unroll
        for (int nt = 0; nt < 4; ++nt)
            acc[mt][nt] = (f32x4){0.f, 0.f, 0.f, 0.f};

    #pragma unroll
    for (int ks = 0; ks < 4; ++ks) {
        const int ko = ks * 32 + quad * 8;
        f16x8 bf[4];
        #pragma unroll
        for (int nt = 0; nt < 4; ++nt) {
            const int c = wv * 64 + nt * 16 + n16;
            bf[nt] = *(const f16x8*)(WABth + c * DIM + ko);
        }
        #pragma unroll
        for (int mt = 0; mt < 4; ++mt) {
            const f16x8 af = *(const f16x8*)&xs[mt * 16 + n16][ko];
            #pragma unroll
            for (int nt = 0; nt < 4; ++nt)
                acc[mt][nt] = __builtin_amdgcn_mfma_f32_16x16x32_f16(
                    af, bf[nt], acc[mt][nt], 0, 0, 0);
        }
    }
    __syncthreads();   // xs reuse hazard: all ds_reads done before overwrite

    // ---- epilogue: +bias, fp16, write into xs/ys out-tiles ----
    #pragma unroll
    for (int nt = 0; nt < 4; ++nt) {
        const int c = wv * 64 + nt * 16 + n16;
        const float bias = (c < 128) ? bA[c] : 0.f;
        #pragma unroll
        for (int mt = 0; mt < 4; ++mt)
            #pragma unroll
            for (int reg = 0; reg < 4; ++reg) {
                const int row = mt * 16 + quad * 4 + reg;
                const __half hv = __float2half(acc[mt][nt][reg] + bias);
                if (c < 128) xs[row][c]       = hv;
                else         ys[row][c - 128] = hv;
            }
    }
    __syncthreads();

    // ---- coalesced read-out: 2048 chunks of 16 B ----
    #pragma unroll
    for (int i = 0; i < 8; ++i) {
        const int chunk = t + i * 256;
        const int row = chunk >> 5;
        const int o   = (chunk & 31) * 8;   // half index 0..255
        if (m0 + row < NN) {
            if (o < 128) {
                const uint4 v = *(const uint4*)&xs[row][o];
                *(uint4*)(A + (size_t)(m0 + row) * DIM + o) = v;
            } else {
                const uint4 v = *(const uint4*)&ys[row][o - 128];
                *(uint4*)(Bv + (size_t)(m0 + row) * DIM + o - 128) = v;
            }
        }
    }
}

// ---------------------------------------------------------------------------
// Gate kernel: 8 edges/wave — 4 slots x 16 lanes, 2 edges per slot.
// Bucketing (atomic + 8-B pair write) inlined: hides under MLP at 0 LDS,
// high occupancy.  (R7-verified; near its VALU/gather floor.)
// ---------------------------------------------------------------------------
__global__ __launch_bounds__(256) void k_gate(
    const int*   __restrict__ ei,  const float* __restrict__ ew,
    const float* __restrict__ ef,
    const __half* __restrict__ A,  const __half* __restrict__ Bv,
    const float* __restrict__ w0p, const float* __restrict__ w1p,
    const float* __restrict__ Wg2, const float* __restrict__ bg2,
    int* __restrict__ deg, int2* __restrict__ pairs)
{
    const int t    = threadIdx.x;
    const int lane = t & 63;
    const int sub  = lane >> 4;
    const int sl   = lane & 15;
    const int c8   = sl * 8;
    const int e0   = (blockIdx.x * 4 + (t >> 6)) * 8 + sub * 2;   // even

    const F8 WG = *(const F8*)(Wg2 + c8);
    const F8 W0 = *(const F8*)(w0p + c8);
    const F8 W1 = *(const F8*)(w1p + c8);
    const float bg2v = bg2[0];
    const float* w0 = (const float*)&W0;
    const float* w1 = (const float*)&W1;
    const float* wg = (const float*)&WG;

    const int2   srcs = *(const int2*)(ei + e0);
    const int2   dsts = *(const int2*)(ei + NE + e0);
    const float4 efv  = *(const float4*)(ef + 2 * e0);
    const float2 ewv  = *(const float2*)(ew + e0);

    const H8 a0 = *(const H8*)(A  + (size_t)dsts.x * DIM + c8);
    const H8 b0 = *(const H8*)(Bv + (size_t)srcs.x * DIM + c8);
    const H8 a1 = *(const H8*)(A  + (size_t)dsts.y * DIM + c8);
    const H8 b1 = *(const H8*)(Bv + (size_t)srcs.y * DIM + c8);

    float p0 = 0.f, p1 = 0.f;
    #pragma unroll
    for (int i = 0; i < 4; ++i) {
        const float2 s0 = __half22float2(__hadd2(a0.h[i], b0.h[i]));
        const float2 s1 = __half22float2(__hadd2(a1.h[i], b1.h[i]));
        const int c0 = 2 * i, c1 = 2 * i + 1;
        float h;
        h = s0.x + efv.x * w0[c0] + efv.y * w1[c0];
        p0 = __builtin_fmaf(gelu_fast(h), wg[c0], p0);
        h = s0.y + efv.x * w0[c1] + efv.y * w1[c1];
        p0 = __builtin_fmaf(gelu_fast(h), wg[c1], p0);
        h = s1.x + efv.z * w0[c0] + efv.w * w1[c0];
        p1 = __builtin_fmaf(gelu_fast(h), wg[c0], p1);
        h = s1.y + efv.z * w0[c1] + efv.w * w1[c1];
        p1 = __builtin_fmaf(gelu_fast(h), wg[c1], p1);
    }
    #pragma unroll
    for (int off = 1; off < 16; off <<= 1) {
        p0 += __shfl_xor(p0, off, 64);
        p1 += __shfl_xor(p1, off, 64);
    }

    if (sl == 0) {
        const float coef0 = ewv.x * sigmoid_fast(p0 + bg2v);
        const float coef1 = ewv.y * sigmoid_fast(p1 + bg2v);
        const int pos0 = atomicAdd(&deg[dsts.x], 1);
        if (pos0 < CAP)
            pairs[(size_t)dsts.x * CAP + pos0] = make_int2(srcs.x, __float_as_int(coef0));
        const int pos1 = atomicAdd(&deg[dsts.y], 1);
        if (pos1 < CAP)
            pairs[(size_t)dsts.y * CAP + pos1] = make_int2(srcs.y, __float_as_int(coef1));
    }
}

// ---------------------------------------------------------------------------
// Fused aggregation + update (R7-verified 2-wave version, unchanged).
// ---------------------------------------------------------------------------
__global__ __launch_bounds__(128, 3) void k_agg_update(
    const int* __restrict__ deg, const int2* __restrict__ pairs,
    const __half* __restrict__ xh, const __half* __restrict__ Wct,
    const float* __restrict__ bu, const float* __restrict__ bpu,
    const float* __restrict__ lng, const float* __restrict__ lnb,
    float* __restrict__ out)
{
    __shared__ __half xt[16][136];       // x tile fp16, +8 pad
    __shared__ __half at[2][16][136];    // per-wave agg tiles fp16
    __shared__ float  sct[2][16];
    __shared__ float  sred_s[2][16];     // per-wave LN partial sums
    __shared__ float  sred_ss[2][16];

    const int t    = threadIdx.x;        // 0..127
    const int w    = t >> 6;             // wave id 0/1
    const int lane = t & 63;
    const int n16  = lane & 15;
    const int quad = lane >> 4;          // 0..3
    const int m0   = blockIdx.x * 16;

    const int slot = quad;               // 4 slots of 16 lanes per wave
    const int sl   = n16;
    const int c8   = sl * 8;

    // ---- per-slot node state: this wave's half of each bucket ----
    int    cnt[4];
    size_t pb[4];
    #pragma unroll
    for (int r = 0; r < 4; ++r) {
        const int lr = r * 4 + slot;
        const int nc = min(m0 + lr, NN - 1);
        const int d  = min(deg[nc], CAP);
        const int h  = ((d + 2) >> 2) << 1;   // ~d/2 rounded to even, <= d
        const int lo = w ? h : 0;
        const int hi = w ? d : h;
        cnt[r] = hi - lo;
        pb[r]  = (size_t)nc * CAP + lo;
    }

    // ---- Phase 0: cooperative xh tile load (256 chunks / 128 thr) ----
    #pragma unroll
    for (int i = 0; i < 2; ++i) {
        const int idx = i * 128 + t;          // 8-half chunk id
        const int row = idx >> 4;             // 16 chunks per row
        const int col = (idx & 15) * 8;
        const int grow = min(m0 + row, NN - 1);
        *(f16x8*)&xt[row][col] = *(const f16x8*)(xh + (size_t)grow * DIM + col);
    }

    // ---- Phase 1: interleaved aggregation, 4 nodes x 4 edges per step ----
    float acc[4][8];
    float scn[4] = {0.f, 0.f, 0.f, 0.f};
    #pragma unroll
    for (int r = 0; r < 4; ++r)
        #pragma unroll
        for (int i = 0; i < 8; ++i) acc[r][i] = 0.f;

    const int cmax = max(max(cnt[0], cnt[1]), max(cnt[2], cnt[3]));

    for (int jj = 0; jj < cmax; jj += 4) {
        // 8 vectorized pair loads (2 entries each); +2 read may overhang the
        // half/bucket by <=2 entries -> masked; pairs carve has tail slack.
        int4 pq0[4], pq1[4];
        #pragma unroll
        for (int r = 0; r < 4; ++r) {
            pq0[r] = *(const int4*)(&pairs[pb[r] + jj]);
            pq1[r] = *(const int4*)(&pairs[pb[r] + jj + 2]);
        }

        // branchless validity: invalid -> gather row 0 (L1-hot) with coef 0
        int   ix[16];
        float cf[16];
        #pragma unroll
        for (int r = 0; r < 4; ++r) {
            const int q = 4 * r;
            const bool v0 = (jj     < cnt[r]);
            const bool v1 = (jj + 1 < cnt[r]);
            const bool v2 = (jj + 2 < cnt[r]);
            const bool v3 = (jj + 3 < cnt[r]);
            ix[q]     = v0 ? pq0[r].x : 0;
            cf[q]     = v0 ? __int_as_float(pq0[r].y) : 0.f;
            ix[q + 1] = v1 ? pq0[r].z : 0;
            cf[q + 1] = v1 ? __int_as_float(pq0[r].w) : 0.f;
            ix[q + 2] = v2 ? pq1[r].x : 0;
            cf[q + 2] = v2 ? __int_as_float(pq1[r].y) : 0.f;
            ix[q + 3] = v3 ? pq1[r].z : 0;
            cf[q + 3] = v3 ? __int_as_float(pq1[r].w) : 0.f;
        }

        // 16 independent row gathers in flight
        H8 xv[16];
        #pragma unroll
        for (int q = 0; q < 16; ++q)
            xv[q] = *(const H8*)(xh + (size_t)ix[q] * DIM + c8);

        #pragma unroll
        for (int r = 0; r < 4; ++r) {
            #pragma unroll
            for (int k = 0; k < 4; ++k) {
                const int   q = 4 * r + k;
                const float c = cf[q];
                #pragma unroll
                for (int i = 0; i < 4; ++i) {
                    const float2 f = __half22float2(xv[q].h[i]);
                    acc[r][2 * i]     = __builtin_fmaf(c, f.x, acc[r][2 * i]);
                    acc[r][2 * i + 1] = __builtin_fmaf(c, f.y, acc[r][2 * i + 1]);
                }
                scn[r] += c;
            }
        }
    }

    #pragma unroll
    for (int r = 0; r < 4; ++r) {
        const int lr = r * 4 + slot;
        f16x8 hv;
        #pragma unroll
        for (int i = 0; i < 8; ++i) hv[i] = (_Float16)acc[r][i];
        *(f16x8*)&at[w][lr][c8] = hv;
        if (sl == 0) sct[w][lr] = scn[r];
    }
    __syncthreads();

    // ---- Phase 2: MFMA, wave w owns output channels [w*64, w*64+64) ----
    f32x4 acc2[4];
    #pragma unroll
    for (int nt = 0; nt < 4; ++nt) acc2[nt] = (f32x4){0.f, 0.f, 0.f, 0.f};

    const int rloc = n16;                     // A-fragment local row
    #pragma unroll
    for (int ks = 0; ks < 4; ++ks) {
        const int ko = ks * 32 + quad * 8;
        const f16x8 af = *(const f16x8*)&xt[rloc][ko];
        #pragma unroll
        for (int nt = 0; nt < 4; ++nt) {
            const int c = w * 64 + nt * 16 + n16;
            const f16x8 bf = *(const f16x8*)(Wct + c * 256 + ko);
            acc2[nt] = __builtin_amdgcn_mfma_f32_16x16x32_f16(af, bf, acc2[nt], 0, 0, 0);
        }
    }
    #pragma unroll
    for (int half = 0; half < 2; ++half) {
        #pragma unroll
        for (int ks = 0; ks < 4; ++ks) {
            const int ko = ks * 32 + quad * 8;
            const f16x8 af = *(const f16x8*)&at[half][rloc][ko];
            #pragma unroll
            for (int nt = 0; nt < 4; ++nt) {
                const int c = w * 64 + nt * 16 + n16;
                const f16x8 bf = *(const f16x8*)(Wct + c * 256 + 128 + ko);
                acc2[nt] = __builtin_amdgcn_mfma_f32_16x16x32_f16(af, bf, acc2[nt], 0, 0, 0);
            }
        }
    }

    // ---- epilogue ----
    int   rl[4];
    float scv[4];
    #pragma unroll
    for (int reg = 0; reg < 4; ++reg) {
        rl[reg]  = quad * 4 + reg;            // local row
        scv[reg] = sct[0][rl[reg]] + sct[1][rl[reg]];
    }

    float yv[4][4];
    float s[4]  = {0.f, 0.f, 0.f, 0.f};
    float ss[4] = {0.f, 0.f, 0.f, 0.f};

    #pragma unroll
    for (int nt = 0; nt < 4; ++nt) {
        const int c = w * 64 + nt * 16 + n16;
        const float buv = bu[c], bpv = bpu[c];
        #pragma unroll
        for (int reg = 0; reg < 4; ++reg) {
            float h = acc2[nt][reg] + buv + scv[reg] * bpv;
            h = gelu_fast(h);
            const float xv = __half2float(xt[rl[reg]][c]);   // residual from LDS
            const float y = xv + h;
            yv[nt][reg] = y;
            s[reg]  += y;
            ss[reg] += y * y;
        }
    }

    #pragma unroll
    for (int reg = 0; reg < 4; ++reg) {
        #pragma unroll
        for (int off = 1; off < 16; off <<= 1) {
            s[reg]  += __shfl_xor(s[reg],  off, 64);
            ss[reg] += __shfl_xor(ss[reg], off, 64);
        }
    }
    if (n16 == 0) {
        #pragma unroll
        for (int reg = 0; reg < 4; ++reg) {
            sred_s[w][rl[reg]]  = s[reg];
            sred_ss[w][rl[reg]] = ss[reg];
        }
    }
    __syncthreads();

    float mu[4], rs[4];
    #pragma unroll
    for (int reg = 0; reg < 4; ++reg) {
        const float stot  = sred_s[0][rl[reg]]  + sred_s[1][rl[reg]];
        const float sstot = sred_ss[0][rl[reg]] + sred_ss[1][rl[reg]];
        mu[reg] = stot * (1.f / DIM);
        const float var = sstot * (1.f / DIM) - mu[reg] * mu[reg];
        rs[reg] = rsqrtf(var + EPS);
    }

    #pragma unroll
    for (int nt = 0; nt < 4; ++nt) {
        const int c = w * 64 + nt * 16 + n16;
        const float gg = lng[c], bb2 = lnb[c];
        #pragma unroll
        for (int reg = 0; reg < 4; ++reg) {
            const int grow = m0 + rl[reg];
            if (grow < NN)
                __builtin_nontemporal_store(
                    (yv[nt][reg] - mu[reg]) * rs[reg] * gg + bb2,
                    &out[(size_t)grow * DIM + c]);
        }
    }
}

// ---------------------------------------------------------------------------
extern "C" void kernel_launch(void* const* d_in, const int* in_sizes, int n_in,
                              void* d_out, int out_size, void* d_ws, size_t ws_size,
                              hipStream_t stream)
{
    const float* x    = (const float*)d_in[0];
    const int*   ei   = (const int*)  d_in[1];
    const float* ew   = (const float*)d_in[2];
    const float* ef   = (const float*)d_in[3];
    const float* Wphi = (const float*)d_in[5];
    const float* bphi = (const float*)d_in[6];
    const float* Wg1  = (const float*)d_in[7];
    const float* bg1  = (const float*)d_in[8];
    const float* bng  = (const float*)d_in[9];
    const float* bnb  = (const float*)d_in[10];
    const float* bnm  = (const float*)d_in[11];
    const float* bnv  = (const float*)d_in[12];
    const float* Wg2  = (const float*)d_in[13];
    const float* bg2  = (const float*)d_in[14];
    const float* Wu   = (const float*)d_in[15];
    const float* bu   = (const float*)d_in[16];
    const float* lng  = (const float*)d_in[17];
    const float* lnb  = (const float*)d_in[18];

    float* out = (float*)d_out;

    char* wsb = (char*)d_ws;
    size_t off = 0;
    auto carve = [&](size_t bytes) -> void* {
        void* p = wsb + off;
        off += (bytes + 255) & ~(size_t)255;
        return p;
    };
    __half* xh    = (__half*)carve((size_t)NN * DIM * 2);
    __half* A     = (__half*)carve((size_t)NN * DIM * 2);
    __half* Bv    = (__half*)carve((size_t)NN * DIM * 2);
    __half* WABth = (__half*)carve(256 * DIM * 2);
    __half* Wct   = (__half*)carve(DIM * 256 * 2);
    float*  bA    = (float*) carve(DIM * 4);
    float*  w0p   = (float*) carve(DIM * 4);
    float*  w1p   = (float*) carve(DIM * 4);
    float*  bpu   = (float*) carve(DIM * 4);
    int*    deg   = (int*)   carve((size_t)NN * 4);
    int2*   pairs = (int2*)  carve((size_t)NN * CAP * 8 + 256);  // +tail slack

    k_prep<<<256, 256, 0, stream>>>(Wg1, bg1, bng, bnb, bnm, bnv,
                                    Wphi, bphi, Wu,
                                    WABth, bA, w0p, w1p, Wct, bpu);
    k_node_mfma<<<(NN + 63) / 64, 256, 0, stream>>>(x, WABth, bA, A, Bv, xh,
                                                    deg);
    k_gate<<<NE / 32, 256, 0, stream>>>(ei, ew, ef, A, Bv, w0p, w1p, Wg2, bg2,
                                        deg, pairs);
    k_agg_update<<<(NN + 15) / 16, 128, 0, stream>>>(deg, pairs, xh, Wct,
                                                     bu, bpu, lng, lnb, out);
}